// Round 17
// baseline (78.305 us; speedup 1.0000x reference)
//
#include <hip/hip_runtime.h>
#include <hip/hip_bf16.h>
#include <math.h>

// ================= complex 2x2 helpers (prep only) =================
struct cf { float x, y; };
__device__ __forceinline__ cf cfmul(cf a, cf b){ return {a.x*b.x - a.y*b.y, a.x*b.y + a.y*b.x}; }
__device__ __forceinline__ cf cfconj(cf a){ return {a.x, -a.y}; }
__device__ __forceinline__ cf cfadd(cf a, cf b){ return {a.x+b.x, a.y+b.y}; }

__device__ __forceinline__ void pmat(int k, cf* P){
    if (k==0){ P[0]={1.f,0.f}; P[1]={0.f,0.f}; P[2]={0.f,0.f}; P[3]={1.f,0.f}; }
    else if (k==1){ P[0]={0.f,0.f}; P[1]={1.f,0.f}; P[2]={1.f,0.f}; P[3]={0.f,0.f}; }
    else if (k==2){ P[0]={0.f,0.f}; P[1]={0.f,-1.f}; P[2]={0.f,1.f}; P[3]={0.f,0.f}; }
    else { P[0]={1.f,0.f}; P[1]={0.f,0.f}; P[2]={0.f,0.f}; P[3]={-1.f,0.f}; }
}
__device__ void mul2(cf* C, const cf* A, const cf* B){
    C[0]=cfadd(cfmul(A[0],B[0]),cfmul(A[1],B[2]));
    C[1]=cfadd(cfmul(A[0],B[1]),cfmul(A[1],B[3]));
    C[2]=cfadd(cfmul(A[2],B[0]),cfmul(A[3],B[2]));
    C[3]=cfadd(cfmul(A[2],B[1]),cfmul(A[3],B[3]));
}
// T[t*4+s] += 0.5 * Re tr(P_t K P_s K^dagger)
__device__ void ptm_acc(float* T, const cf* K){
    cf Kd[4] = {cfconj(K[0]), cfconj(K[2]), cfconj(K[1]), cfconj(K[3])};
    for (int s=0;s<4;s++){
        cf Ps[4]; pmat(s,Ps);
        cf t1[4], t2[4];
        mul2(t1, K, Ps);
        mul2(t2, t1, Kd);
        for (int t=0;t<4;t++){
            cf Pt[4]; pmat(t,Pt);
            float re = Pt[0].x*t2[0].x - Pt[0].y*t2[0].y
                     + Pt[1].x*t2[2].x - Pt[1].y*t2[2].y
                     + Pt[2].x*t2[1].x - Pt[2].y*t2[1].y
                     + Pt[3].x*t2[3].x - Pt[3].y*t2[3].y;
            T[t*4+s] += 0.5f*re;
        }
    }
}
__device__ void rmm4(float* C, const float* A, const float* B){
    for (int i=0;i<4;i++) for (int j=0;j<4;j++){
        float s=0.f;
        for (int k=0;k<4;k++) s += A[i*4+k]*B[k*4+j];
        C[i*4+j]=s;
    }
}

// prep compute: threads 0..30 fill sm[0..495] with REAL Pauli-transfer mats.
// sm[(l*10+q)*16..] = Tnoise1 * Trot(l,q); sm[480..] = Tnoise2 (N2).
__device__ void prep_compute(float* sm, const float* __restrict__ wts, int tid){
    if (tid < 31){
        const float GA = -expm1f(-2.0000000000000002e-06f);   // 1-exp(-GATE/T1)
        const float GP = -expm1f(-1.4285714285714286e-06f);   // 1-exp(-GATE/T2)
        float sa = sqrtf(1.f-GA), spp = sqrtf(1.f-GP);
        float p = (tid==30) ? 0.01f : 0.001f;
        float f = 1.f - (4.f/3.f)*p;
        float Tn[16] = {0};
        Tn[0]      = 1.f;
        Tn[1*4+1]  = spp*sa*f;
        Tn[2*4+2]  = spp*sa*f;
        Tn[3*4+3]  = (1.f-GA)*f;
        Tn[3*4+0]  = GA;
        if (tid == 30){
            for (int i=0;i<16;i++) sm[480+i] = Tn[i];
        } else {
            float phi = wts[tid*3+0], th = wts[tid*3+1], om = wts[tid*3+2];
            float ct = cosf(0.5f*th), st = sinf(0.5f*th);
            cf ep = {cosf(0.5f*(phi+om)), -sinf(0.5f*(phi+om))};
            cf em = {cosf(0.5f*(phi-om)),  sinf(0.5f*(phi-om))};
            cf U[4];
            U[0] = { ep.x*ct,  ep.y*ct};
            U[1] = {-em.x*st, -em.y*st};
            U[2] = { em.x*st, -em.y*st};
            U[3] = { ep.x*ct, -ep.y*ct};
            float Tr[16] = {0};
            ptm_acc(Tr, U);                 // unitary: single Kraus
            float S[16]; rmm4(S, Tn, Tr);   // rot first, then noise
            for (int i=0;i<16;i++) sm[tid*16+i] = S[i];
        }
    }
}

// LDS swizzle on 12-bit float index: XOR bits 9..11 into 2..4 (float4-preserving)
__device__ __forceinline__ unsigned swz(unsigned t){ return t ^ ((t>>7)&0x1Cu); }

#define ALONG_A(Mp) { _Pragma("unroll") for (int db_=0; db_<4; db_++){ \
    float a0=v[db_], a1=v[4+db_], a2=v[8+db_], a3=v[12+db_]; \
    _Pragma("unroll") for (int dp_=0; dp_<4; dp_++){ \
        v[dp_*4+db_] = (Mp)[dp_*4+0]*a0 + (Mp)[dp_*4+1]*a1 + (Mp)[dp_*4+2]*a2 + (Mp)[dp_*4+3]*a3; } } }

#define ALONG_B(Mp) { _Pragma("unroll") for (int da_=0; da_<4; da_++){ \
    float a0=v[da_*4+0], a1=v[da_*4+1], a2=v[da_*4+2], a3=v[da_*4+3]; \
    _Pragma("unroll") for (int dp_=0; dp_<4; dp_++){ \
        v[da_*4+dp_] = (Mp)[dp_*4+0]*a0 + (Mp)[dp_*4+1]*a1 + (Mp)[dp_*4+2]*a2 + (Mp)[dp_*4+3]*a3; } } }

// transposed variants (M^T applied along the axis): index M[d*4+dp] instead of M[dp*4+d]
#define ALONG_AT(Mp) { _Pragma("unroll") for (int db_=0; db_<4; db_++){ \
    float a0=v[db_], a1=v[4+db_], a2=v[8+db_], a3=v[12+db_]; \
    _Pragma("unroll") for (int dp_=0; dp_<4; dp_++){ \
        v[dp_*4+db_] = (Mp)[0*4+dp_]*a0 + (Mp)[1*4+dp_]*a1 + (Mp)[2*4+dp_]*a2 + (Mp)[3*4+dp_]*a3; } } }

#define ALONG_BT(Mp) { _Pragma("unroll") for (int da_=0; da_<4; da_++){ \
    float a0=v[da_*4+0], a1=v[da_*4+1], a2=v[da_*4+2], a3=v[da_*4+3]; \
    _Pragma("unroll") for (int dp_=0; dp_<4; dp_++){ \
        v[da_*4+dp_] = (Mp)[0*4+dp_]*a0 + (Mp)[1*4+dp_]*a1 + (Mp)[2*4+dp_]*a2 + (Mp)[3*4+dp_]*a3; } } }

#define CNOT_PERM { float t0; \
    t0=v[4];  v[4]=v[5];   v[5]=t0;  \
    t0=v[8];  v[8]=v[9];   v[9]=t0;  \
    t0=v[2];  v[2]=v[14];  v[14]=t0; \
    t0=v[3];  v[3]=v[15];  v[15]=t0; \
    t0=v[6];  v[6]=v[11];  v[11]=t0; \
    t0=v[7];  v[7]=-v[10]; v[10]=-t0; }

// window bit tables
__device__ __constant__ const int cA_PA[5] = {0,10,8,6,4}, cA_PB[5] = {10,8,6,4,2};
__device__ __constant__ const int cB_PA[5] = {2,10,8,6,4}, cB_PB[5] = {10,8,6,4,0};

// shared op-chain (5 ops of one phase window). ISB selects bit tables; LAYER selects mats.
template<int LAYER, int ISB>
__device__ __forceinline__ void run_ops(float* tile, const float* sm, int tid){
#pragma unroll
    for (int i=0; i<5; i++){
        const int pa = ISB ? cB_PA[i] : cA_PA[i];
        const int pb = ISB ? cB_PB[i] : cA_PB[i];
        const int mA = (!ISB && i==0) ? LAYER*160 : -1;               // rot(l,0) on control
        const int mB = !ISB ? (LAYER*10 + i + 1)*16
                            : ((i < 4) ? (LAYER*10 + 6 + i)*16 : -1); // rot(l,6..9)
        const int lo = pa < pb ? pa : pb, hi = pa < pb ? pb : pa;
        unsigned g8 = (unsigned)tid;
        unsigned xx = ((g8 >> lo) << (lo+2)) | (g8 & ((1u<<lo)-1u));
        xx = ((xx >> hi) << (hi+2)) | (xx & ((1u<<hi)-1u));
        unsigned adr[16];
        float v[16];
#pragma unroll
        for (int d=0; d<16; d++){
            unsigned t = xx | ((unsigned)(d>>2) << pa) | ((unsigned)(d&3) << pb);
            adr[d] = swz(t);
            v[d] = tile[adr[d]];
        }
        if (mA >= 0){ const float* M = sm + mA; ALONG_A(M); }
        if (mB >= 0){ const float* M = sm + mB; ALONG_B(M); }
        CNOT_PERM
        { const float* M = sm + 480; ALONG_B(M); ALONG_A(M); }   // N2 target, N2 control
#pragma unroll
        for (int d=0; d<16; d++) tile[adr[d]] = v[d];
        __syncthreads();
    }
}

// ================= P0: dual-purpose 512-thread kernel =================
// Waves 0-3 (tid<256): sim init + L1 first half (A-layout, block -> bits 12..19).
// Waves 4-7, blocks 0..35: adjoint transport through L3:
//   blk 0..11 : V_k    = P5win^T e_k          (B-chain, LAYER 2)  -> Vbuf[4096][16] (k-contig)
//   blk 12..27: P4T_d  = P4win^T e_(d05,I4)   (A-chain, LAYER 2)  -> P4Tbuf[d][4096]
//   blk 28..35: VA_j   = P4win^T e_j (q1..4)  (A-chain, LAYER 2)  -> VAbuf[j][4096]
// Both halves execute exactly 1 + 5 __syncthreads (wave-aligned split, no deadlock).
__global__ void __launch_bounds__(512, 1)
phase0_dual(float* __restrict__ rho, const float* __restrict__ wts,
            float* __restrict__ smg, float* __restrict__ Vbuf,
            float* __restrict__ P4Tbuf, float* __restrict__ VAbuf)
{
    __shared__ __align__(16) float tileS[4096];
    __shared__ __align__(16) float tileV[4096];
    __shared__ __align__(16) float sm[496];
    int tid = threadIdx.x;
    unsigned blk = blockIdx.x;
    const bool lower = (tid < 256);
    const int lt = tid & 255;

    prep_compute(sm, wts, tid);            // wave 0 only

    if (lower){
        unsigned bo = blk << 12;
        // c_s = 1 for s in {I,Z}^10 (digit bits equal), else 0
#pragma unroll
        for (int r=0; r<16; r++){
            unsigned u = lt + 256u*r;
            unsigned g = u | bo;
            unsigned e = g & 0x55555u, o = (g>>1) & 0x55555u;
            tileS[swz(u)] = (e==o) ? 1.f : 0.f;
        }
    } else if (blk < 36){
        unsigned sk;
        if (blk < 12){
            sk = (((blk & 1u) ? 3u : 1u) << (2*(blk>>1)));            // B-window slot blk>>1
        } else if (blk < 28){
            sk = blk - 12u;                                            // e_(d05, I4): u = d05
        } else {
            unsigned j = blk - 28u;                                    // q=(j>>1)+1 -> slot 6-q
            sk = (((j & 1u) ? 3u : 1u) << (2*(6 - ((j>>1)+1))));
        }
#pragma unroll
        for (int r=0; r<16; r++){
            unsigned u = lt + 256u*r;
            tileV[swz(u)] = (u == sk) ? 1.f : 0.f;
        }
    }
    __syncthreads();                                       // barrier A (sm + tiles ready)

    if (blk == 0 && lower && lt < 124)                     // cache sm for later kernels
        reinterpret_cast<float4*>(smg)[lt] = *reinterpret_cast<const float4*>(&sm[4*lt]);

#pragma unroll
    for (int it=0; it<5; ++it){
        if (lower){
            // sim op it (A-layout, LAYER 0)
            const int i = it;
            const int pa = cA_PA[i], pb = cA_PB[i];
            const int mA = (i==0) ? 0 : -1;
            const int mB = (i + 1)*16;
            const int lo = pa < pb ? pa : pb, hi = pa < pb ? pb : pa;
            unsigned g8 = (unsigned)lt;
            unsigned xx = ((g8 >> lo) << (lo+2)) | (g8 & ((1u<<lo)-1u));
            xx = ((xx >> hi) << (hi+2)) | (xx & ((1u<<hi)-1u));
            unsigned adr[16];
            float v[16];
#pragma unroll
            for (int d=0; d<16; d++){
                unsigned t = xx | ((unsigned)(d>>2) << pa) | ((unsigned)(d&3) << pb);
                adr[d] = swz(t);
                v[d] = tileS[adr[d]];
            }
            if (mA >= 0){ const float* M = sm + mA; ALONG_A(M); }
            { const float* M = sm + mB; ALONG_B(M); }
            CNOT_PERM
            { const float* M = sm + 480; ALONG_B(M); ALONG_A(M); }
#pragma unroll
            for (int d=0; d<16; d++) tileS[adr[d]] = v[d];
        } else if (blk < 36){
            // adjoint op (reverse order): i = 4-it; chain = B for blk<12, else A
            const bool bch = (blk < 12);
            const int i = 4 - it;
            const int pa = bch ? cB_PA[i] : cA_PA[i];
            const int pb = bch ? cB_PB[i] : cA_PB[i];
            const int lo = pa < pb ? pa : pb, hi = pa < pb ? pb : pa;
            unsigned g8 = (unsigned)lt;
            unsigned xx = ((g8 >> lo) << (lo+2)) | (g8 & ((1u<<lo)-1u));
            xx = ((xx >> hi) << (hi+2)) | (xx & ((1u<<hi)-1u));
            unsigned adr[16];
            float v[16];
#pragma unroll
            for (int d=0; d<16; d++){
                unsigned t = xx | ((unsigned)(d>>2) << pa) | ((unsigned)(d&3) << pb);
                adr[d] = swz(t);
                v[d] = tileV[adr[d]];
            }
            { const float* M = sm + 480; ALONG_AT(M); ALONG_BT(M); }  // N2a^T, N2b^T
            CNOT_PERM                                                  // self-transpose
            const int mB = bch ? ((i < 4) ? (26 + i)*16 : -1) : (21 + i)*16;
            if (mB >= 0){ const float* M = sm + mB; ALONG_BT(M); }     // rot^T (target)
            if (!bch && i == 0){ const float* M = sm + 320; ALONG_AT(M); } // rot(2,0)^T
#pragma unroll
            for (int d=0; d<16; d++) tileV[adr[d]] = v[d];
        }
        __syncthreads();
    }

    if (lower){
        unsigned bo = blk << 12;
#pragma unroll
        for (int r=0; r<4; r++){
            unsigned u = 4u*(lt + 256u*r);
            *reinterpret_cast<float4*>(rho + (u | bo)) =
                *reinterpret_cast<const float4*>(&tileS[swz(u)]);
        }
    } else if (blk < 36){
        if (blk < 12){
            // transposed layout: Vbuf[vidx*16 + k] (k contiguous, 12 used of 16)
#pragma unroll
            for (int r=0; r<16; r++){
                unsigned u = lt + 256u*r;
                Vbuf[u*16u + blk] = tileV[swz(u)];
            }
        } else {
            float* dst = (blk < 28) ? (P4Tbuf + ((int)blk-12)*4096)
                                    : (VAbuf + ((int)blk-28)*4096);
#pragma unroll
            for (int r=0; r<4; r++){
                unsigned u = 4u*(lt + 256u*r);
                *reinterpret_cast<float4*>(dst + u) =
                    *reinterpret_cast<const float4*>(&tileV[swz(u)]);
            }
        }
    }
}

// ================= sim phase kernel P1..P3 =================
// Phase A (ISB=0): tile = bits 0..11 (qubits 0,5,4,3,2,1); block -> bits 12..19.
// Phase B (ISB=1): tile = bits 0..3 + 12..19 (qubits 0,5,9,8,7,6); block -> bits 4..11.
// MODE 4 (P3D = L2-B, last phase): after ops, contract with P4T/V/VA -> part[20][256];
//   NO rho store (L3 fully folded into the adjoint weights).
template<int LAYER, int ISB, int MODE>
__global__ void __launch_bounds__(256)
fused6(float* __restrict__ rho, const float* __restrict__ smg,
       const float* __restrict__ Vbuf, const float* __restrict__ P4Tbuf,
       const float* __restrict__ VAbuf, float* __restrict__ part)
{
    __shared__ __align__(16) float tile[4096];
    __shared__ __align__(16) float sm[496];
    int tid = threadIdx.x;
    unsigned blk = blockIdx.x;

    if (tid < 124)
        reinterpret_cast<float4*>(sm)[tid] = reinterpret_cast<const float4*>(smg)[tid];

    unsigned bo = blk << (ISB ? 4 : 12);
#pragma unroll
    for (int r=0; r<4; r++){
        unsigned u = 4u*(tid + 256u*r);
        unsigned g = ISB ? ((u & 15u) | ((u>>4)<<12) | bo) : (u | bo);
        *reinterpret_cast<float4*>(&tile[swz(u)]) = *reinterpret_cast<const float4*>(rho + g);
    }
    __syncthreads();

    run_ops<LAYER, ISB>(tile, sm, tid);

    if (MODE == 4){
        // obs_k = sum_{d05,d9876} V_k[d05,d9876] * sum_{d0d5} P4T_{d05}[(d0d5)|b<<4] * tile[(d0d5)|d9876<<4]
        __shared__ float p4tb[256];     // [d05][e=d0d5]
        __shared__ float redva[128];
        __shared__ float redw[48];
        p4tb[tid] = P4Tbuf[(tid>>4)*4096 + (int)blk*16 + (tid&15)];
        if (tid < 128)
            redva[tid] = VAbuf[(tid>>4)*4096 + (int)blk*16 + (tid&15)] * tile[swz((unsigned)(tid&15))];
        __syncthreads();
        if (tid < 8){
            float s = 0.f;
#pragma unroll
            for (int e=0;e<16;e++) s += redva[tid*16+e];
            part[(12+tid)*256 + (int)blk] = s;      // pass-through obs (q1..4)
        }
        float sk[12];
#pragma unroll
        for (int k=0;k<12;k++) sk[k] = 0.f;
        const float* pr = &p4tb[(tid&15)*16];       // d05 = tid&15
        for (int j=0;j<16;j++){
            int d9876 = (tid>>4) + 16*j;
            float A = 0.f;
#pragma unroll
            for (int e=0;e<16;e++) A += pr[e] * tile[swz((unsigned)(e | (d9876<<4)))];
            int vidx = tid + (j<<8);                // = (tid&15) | d9876<<4
            const float4* vp = reinterpret_cast<const float4*>(Vbuf + (size_t)vidx*16);
            float4 v0 = vp[0], v1 = vp[1], v2 = vp[2];   // coalesced: lanes -> consecutive 64B
            sk[0] += v0.x*A; sk[1] += v0.y*A; sk[2]  += v0.z*A; sk[3]  += v0.w*A;
            sk[4] += v1.x*A; sk[5] += v1.y*A; sk[6]  += v1.z*A; sk[7]  += v1.w*A;
            sk[8] += v2.x*A; sk[9] += v2.y*A; sk[10] += v2.z*A; sk[11] += v2.w*A;
        }
        int lane = tid & 63, wv = tid >> 6;
#pragma unroll
        for (int k=0;k<12;k++){
            float v = sk[k];
            v += __shfl_down(v,32); v += __shfl_down(v,16); v += __shfl_down(v,8);
            v += __shfl_down(v,4);  v += __shfl_down(v,2);  v += __shfl_down(v,1);
            if (lane == 0) redw[wv*12 + k] = v;
        }
        __syncthreads();
        if (tid < 12)
            part[tid*256 + (int)blk] = redw[tid] + redw[12+tid] + redw[24+tid] + redw[36+tid];
        return;                                     // rho is dead: no store
    }

#pragma unroll
    for (int r=0; r<4; r++){
        unsigned u = 4u*(tid + 256u*r);
        unsigned g = ISB ? ((u & 15u) | ((u>>4)<<12) | bo) : (u | bo);
        *reinterpret_cast<float4*>(rho + g) = *reinterpret_cast<const float4*>(&tile[swz(u)]);
    }
}

// ================= logits (grid 2048, 1 batch/block): part-reduce + feats =================
__global__ void __launch_bounds__(256)
logits_mega(const float* __restrict__ part,
            const float* __restrict__ x, const float* __restrict__ bvec,
            const float* __restrict__ w, float* __restrict__ out)
{
    __shared__ float xs[1024];
    __shared__ float cvw[20];
    __shared__ float redl[80];
    __shared__ float redp[160];
    int tid = threadIdx.x;
    int b = (int)blockIdx.x;

    // reduce part[20][256] -> 20 observables (L2-broadcast, 20 KB)
    if (tid < 160){
        int k = tid >> 3, m = tid & 7;
        float s = 0.f;
#pragma unroll
        for (int i=0; i<32; i++) s += part[k*256 + m*32 + i];
        redp[tid] = s;
    }
    {
        float4 xv = reinterpret_cast<const float4*>(x + (size_t)b*1024)[tid];
        float4 bv = reinterpret_cast<const float4*>(bvec)[tid];
        xs[tid*4+0] = xv.x + bv.x;
        xs[tid*4+1] = xv.y + bv.y;
        xs[tid*4+2] = xv.z + bv.z;
        xs[tid*4+3] = xv.w + bv.w;
    }
    __syncthreads();
    if (tid < 20){
        float s = 0.f;
#pragma unroll
        for (int m=0; m<8; m++) s += redp[tid*8 + m];
        const int TQ[6] = {0,5,9,8,7,6};
        int ci;
        if (tid < 12) ci = 2*TQ[tid>>1] + (tid & 1);          // window obs
        else { int j = tid - 12; ci = 2*((j>>1)+1) + (j & 1); } // pass-through q1..4
        cvw[ci] = ((ci & 1) ? 0.96f : 1.0f) * w[ci] * s;      // readout bitflip folded into Z
    }

    float aX[10] = {0,0,0,0,0,0,0,0,0,0};
    float aZ[10] = {0,0,0,0,0,0,0,0,0,0};
#pragma unroll
    for (int r=0; r<4; r++){
        int m = tid + r*256;
        float xm = xs[m];
        float x2 = xm*xm;
#pragma unroll
        for (int q=0; q<10; q++){
            int bit = 1 << (9-q);
            aX[q] += xm * xs[m ^ bit];
            aZ[q] += (m & bit) ? -x2 : x2;
        }
    }
    int lane = tid & 63, wv = tid >> 6;
#pragma unroll
    for (int kk=0; kk<20; kk++){
        float v = (kk < 10) ? aX[kk] : aZ[kk-10];
        v += __shfl_down(v, 32); v += __shfl_down(v, 16); v += __shfl_down(v, 8);
        v += __shfl_down(v, 4);  v += __shfl_down(v, 2);  v += __shfl_down(v, 1);
        if (lane == 0) redl[wv*20 + kk] = v;
    }
    __syncthreads();
    if (tid == 0){
        float logit = 0.f;
#pragma unroll
        for (int q=0; q<10; q++){
            float FX = redl[q]    + redl[20+q] + redl[40+q] + redl[60+q];
            float FZ = redl[10+q] + redl[30+q] + redl[50+q] + redl[70+q];
            logit += cvw[2*q] * FX + cvw[2*q+1] * FZ;
        }
        out[b] = 1.f / (1.f + expf(-logit));
    }
}

// ================= launch =================
extern "C" void kernel_launch(void* const* d_in, const int* in_sizes, int n_in,
                              void* d_out, int out_size, void* d_ws, size_t ws_size,
                              hipStream_t stream) {
    const float* x    = (const float*)d_in[0];   // [2048,1024]
    const float* bvec = (const float*)d_in[1];   // [1024]
    const float* w    = (const float*)d_in[2];   // [20]
    const float* cw   = (const float*)d_in[3];   // [3,10,3]
    float* out = (float*)d_out;

    char* ws = (char*)d_ws;
    float* rho    = (float*)ws;                                     // 2^20 floats = 4 MB
    float* smg    = (float*)(ws + (size_t)(1u<<20)*sizeof(float));  // 496 floats (PTM cache)
    float* part   = smg + 512;                                      // 20*256 floats
    float* Vbuf   = part + 5120;                                    // 4096*16 (transposed, k-contig)
    float* P4Tbuf = Vbuf + 4096*16;                                 // 16*4096
    float* VAbuf  = P4Tbuf + 16*4096;                               // 8*4096
    (void)ws_size; (void)in_sizes; (void)n_in; (void)out_size;

    phase0_dual<<<256, 512, 0, stream>>>(rho, cw, smg, Vbuf, P4Tbuf, VAbuf);     // P0 + adjoints
    fused6<0,1,0><<<256, 256, 0, stream>>>(rho, smg, Vbuf, P4Tbuf, VAbuf, part); // P1: L1-B
    fused6<1,0,0><<<256, 256, 0, stream>>>(rho, smg, Vbuf, P4Tbuf, VAbuf, part); // P2: L2-A
    fused6<1,1,4><<<256, 256, 0, stream>>>(rho, smg, Vbuf, P4Tbuf, VAbuf, part); // P3D: L2-B + dots
    logits_mega<<<2048, 256, 0, stream>>>(part, x, bvec, w, out);
}

// Round 18
// 66.385 us; speedup vs baseline: 1.1796x; 1.1796x over previous
//
#include <hip/hip_runtime.h>
#include <hip/hip_bf16.h>
#include <math.h>

// ================= complex 2x2 helpers (prep only) =================
struct cf { float x, y; };
__device__ __forceinline__ cf cfmul(cf a, cf b){ return {a.x*b.x - a.y*b.y, a.x*b.y + a.y*b.x}; }
__device__ __forceinline__ cf cfconj(cf a){ return {a.x, -a.y}; }
__device__ __forceinline__ cf cfadd(cf a, cf b){ return {a.x+b.x, a.y+b.y}; }

__device__ __forceinline__ void pmat(int k, cf* P){
    if (k==0){ P[0]={1.f,0.f}; P[1]={0.f,0.f}; P[2]={0.f,0.f}; P[3]={1.f,0.f}; }
    else if (k==1){ P[0]={0.f,0.f}; P[1]={1.f,0.f}; P[2]={1.f,0.f}; P[3]={0.f,0.f}; }
    else if (k==2){ P[0]={0.f,0.f}; P[1]={0.f,-1.f}; P[2]={0.f,1.f}; P[3]={0.f,0.f}; }
    else { P[0]={1.f,0.f}; P[1]={0.f,0.f}; P[2]={0.f,0.f}; P[3]={-1.f,0.f}; }
}
__device__ void mul2(cf* C, const cf* A, const cf* B){
    C[0]=cfadd(cfmul(A[0],B[0]),cfmul(A[1],B[2]));
    C[1]=cfadd(cfmul(A[0],B[1]),cfmul(A[1],B[3]));
    C[2]=cfadd(cfmul(A[2],B[0]),cfmul(A[3],B[2]));
    C[3]=cfadd(cfmul(A[2],B[1]),cfmul(A[3],B[3]));
}
// T[t*4+s] += 0.5 * Re tr(P_t K P_s K^dagger)
__device__ void ptm_acc(float* T, const cf* K){
    cf Kd[4] = {cfconj(K[0]), cfconj(K[2]), cfconj(K[1]), cfconj(K[3])};
    for (int s=0;s<4;s++){
        cf Ps[4]; pmat(s,Ps);
        cf t1[4], t2[4];
        mul2(t1, K, Ps);
        mul2(t2, t1, Kd);
        for (int t=0;t<4;t++){
            cf Pt[4]; pmat(t,Pt);
            float re = Pt[0].x*t2[0].x - Pt[0].y*t2[0].y
                     + Pt[1].x*t2[2].x - Pt[1].y*t2[2].y
                     + Pt[2].x*t2[1].x - Pt[2].y*t2[1].y
                     + Pt[3].x*t2[3].x - Pt[3].y*t2[3].y;
            T[t*4+s] += 0.5f*re;
        }
    }
}
__device__ void rmm4(float* C, const float* A, const float* B){
    for (int i=0;i<4;i++) for (int j=0;j<4;j++){
        float s=0.f;
        for (int k=0;k<4;k++) s += A[i*4+k]*B[k*4+j];
        C[i*4+j]=s;
    }
}

// in-kernel prep: threads 0..30 fill sm[0..495] with REAL Pauli-transfer mats.
// sm[(l*10+q)*16..] = Tnoise1 * Trot(l,q); sm[480..] = Tnoise2 (N2).
__device__ void prep_sm(float* sm, const float* __restrict__ wts, int tid){
    if (tid < 31){
        const float GA = -expm1f(-2.0000000000000002e-06f);   // 1-exp(-GATE/T1)
        const float GP = -expm1f(-1.4285714285714286e-06f);   // 1-exp(-GATE/T2)
        float sa = sqrtf(1.f-GA), spp = sqrtf(1.f-GP);
        float p = (tid==30) ? 0.01f : 0.001f;
        float f = 1.f - (4.f/3.f)*p;
        float Tn[16] = {0};
        Tn[0]      = 1.f;
        Tn[1*4+1]  = spp*sa*f;
        Tn[2*4+2]  = spp*sa*f;
        Tn[3*4+3]  = (1.f-GA)*f;
        Tn[3*4+0]  = GA;
        if (tid == 30){
            for (int i=0;i<16;i++) sm[480+i] = Tn[i];
        } else {
            float phi = wts[tid*3+0], th = wts[tid*3+1], om = wts[tid*3+2];
            float ct = cosf(0.5f*th), st = sinf(0.5f*th);
            cf ep = {cosf(0.5f*(phi+om)), -sinf(0.5f*(phi+om))};
            cf em = {cosf(0.5f*(phi-om)),  sinf(0.5f*(phi-om))};
            cf U[4];
            U[0] = { ep.x*ct,  ep.y*ct};
            U[1] = {-em.x*st, -em.y*st};
            U[2] = { em.x*st, -em.y*st};
            U[3] = { ep.x*ct, -ep.y*ct};
            float Tr[16] = {0};
            ptm_acc(Tr, U);                 // unitary: single Kraus
            float S[16]; rmm4(S, Tn, Tr);   // rot first, then noise
            for (int i=0;i<16;i++) sm[tid*16+i] = S[i];
        }
    }
}

// LDS swizzle on 12-bit float index: XOR bits 9..11 into 2..4 (float4-preserving)
__device__ __forceinline__ unsigned swz(unsigned t){ return t ^ ((t>>7)&0x1Cu); }

#define ALONG_A(Mp) { _Pragma("unroll") for (int db_=0; db_<4; db_++){ \
    float a0=v[db_], a1=v[4+db_], a2=v[8+db_], a3=v[12+db_]; \
    _Pragma("unroll") for (int dp_=0; dp_<4; dp_++){ \
        v[dp_*4+db_] = (Mp)[dp_*4+0]*a0 + (Mp)[dp_*4+1]*a1 + (Mp)[dp_*4+2]*a2 + (Mp)[dp_*4+3]*a3; } } }

#define ALONG_B(Mp) { _Pragma("unroll") for (int da_=0; da_<4; da_++){ \
    float a0=v[da_*4+0], a1=v[da_*4+1], a2=v[da_*4+2], a3=v[da_*4+3]; \
    _Pragma("unroll") for (int dp_=0; dp_<4; dp_++){ \
        v[da_*4+dp_] = (Mp)[dp_*4+0]*a0 + (Mp)[dp_*4+1]*a1 + (Mp)[dp_*4+2]*a2 + (Mp)[dp_*4+3]*a3; } } }

// ================= fused phase kernel (Pauli rep, fully specialized) =================
// c layout (float index, 20 bits): qubit q at position p(q): q0->0,q5->1,q4->2,q3->3,
//   q2->4,q1->5,q9->6,q8->7,q7->8,q6->9; digit (2-bit Pauli idx: I=0,X=1,Y=2,Z=3)
//   at bits (2p, 2p+1).
// Phase A (ISB=0): tile = bits 0..11 (qubits 0,5,4,3,2,1); block -> bits 12..19.
// Phase B (ISB=1): tile = bits 0..3 + 12..19 (qubits 0,5,9,8,7,6); block -> bits 4..11.
// MODE 2 (last phase): grid=9 LUT blocks, trace = direct entry reads, no store.
template<int LAYER, int ISB, int DOINIT, int MODE>
__global__ void __launch_bounds__(256)
fused6(float* __restrict__ rho, const float* __restrict__ wts, float* __restrict__ cvec)
{
    __shared__ __align__(16) float tile[4096];
    __shared__ float sm[31*16];
    int tid = threadIdx.x;
    unsigned blk = blockIdx.x;
    if (MODE == 2){
        const unsigned LUT[9] = {0,1,3,4,12,16,48,64,192};
        blk = LUT[blockIdx.x];
    }

    prep_sm(sm, wts, tid);      // wave 0 only; waves 1-3 fall through to loads

    unsigned bo = blk << (ISB ? 4 : 12);
    if (DOINIT){
        // c_s = 1 for s in {I,Z}^10 (digit bits equal), else 0
#pragma unroll
        for (int r=0; r<16; r++){
            unsigned u = tid + 256u*r;
            unsigned g = u | bo;
            unsigned e = g & 0x55555u, o = (g>>1) & 0x55555u;
            tile[swz(u)] = (e==o) ? 1.f : 0.f;
        }
    } else {
#pragma unroll
        for (int r=0; r<4; r++){
            unsigned u = 4u*(tid + 256u*r);
            unsigned g = ISB ? ((u & 15u) | ((u>>4)<<12) | bo) : (u | bo);
            *reinterpret_cast<float4*>(&tile[swz(u)]) = *reinterpret_cast<const float4*>(rho + g);
        }
    }
    __syncthreads();

    // op tables (tile bit positions of control/target digit pairs) — compile-time
    constexpr int A_PA[5] = {0,10,8,6,4}, A_PB[5] = {10,8,6,4,2};
    constexpr int B_PA[5] = {2,10,8,6,4}, B_PB[5] = {10,8,6,4,0};

#pragma unroll
    for (int i=0; i<5; i++){
        const int pa = ISB ? B_PA[i] : A_PA[i];
        const int pb = ISB ? B_PB[i] : A_PB[i];
        const int mA = (!ISB && i==0) ? LAYER*160 : -1;               // rot(l,0) on control
        const int mB = !ISB ? (LAYER*10 + i + 1)*16
                            : ((i < 4) ? (LAYER*10 + 6 + i)*16 : -1); // rot(l,6..9)
        const int lo = pa < pb ? pa : pb, hi = pa < pb ? pb : pa;
        unsigned g8 = (unsigned)tid;
        unsigned xx = ((g8 >> lo) << (lo+2)) | (g8 & ((1u<<lo)-1u));
        xx = ((xx >> hi) << (hi+2)) | (xx & ((1u<<hi)-1u));
        unsigned adr[16];
        float v[16];
#pragma unroll
        for (int d=0; d<16; d++){
            unsigned t = xx | ((unsigned)(d>>2) << pa) | ((unsigned)(d&3) << pb);
            adr[d] = swz(t);
            v[d] = tile[adr[d]];
        }
        if (mA >= 0){ const float* M = sm + mA; ALONG_A(M); }
        if (mB >= 0){ const float* M = sm + mB; ALONG_B(M); }
        { // CNOT Pauli-basis signed permutation (v[4*pc+pt], I=0,X=1,Y=2,Z=3):
          // (X,I)<->(X,X) (Y,I)<->(Y,X) (I,Y)<->(Z,Y) (I,Z)<->(Z,Z)
          // (X,Y)<->(Y,Z) (X,Z)<->-(Y,Y); fixed: (I,I),(I,X),(Z,I),(Z,X)
            float t0;
            t0=v[4];  v[4]=v[5];   v[5]=t0;
            t0=v[8];  v[8]=v[9];   v[9]=t0;
            t0=v[2];  v[2]=v[14];  v[14]=t0;
            t0=v[3];  v[3]=v[15];  v[15]=t0;
            t0=v[6];  v[6]=v[11];  v[11]=t0;
            t0=v[7];  v[7]=-v[10]; v[10]=-t0;
        }
        { const float* M = sm + 480; ALONG_B(M); ALONG_A(M); }   // N2 target, N2 control
#pragma unroll
        for (int d=0; d<16; d++) tile[adr[d]] = v[d];
        __syncthreads();
    }

    if (MODE != 2){
#pragma unroll
        for (int r=0; r<4; r++){
            unsigned u = 4u*(tid + 256u*r);
            unsigned g = ISB ? ((u & 15u) | ((u>>4)<<12) | bo) : (u | bo);
            *reinterpret_cast<float4*>(rho + g) = *reinterpret_cast<const float4*>(&tile[swz(u)]);
        }
        return;
    }

    // ---- MODE 2: trace = direct coefficient reads; c is dead, no store ----
    // exps(X_q) = c[digit q = X, rest I]; exps(Z_q) = c[digit q = Z, rest I].
    // Tile slot i -> qubit {0,5,9,8,7,6}; block digit j -> qubit {4,3,2,1}.
    if (blk == 0){
        if (tid < 12){
            const int TQ[6] = {0,5,9,8,7,6};
            int i = tid >> 1, isZ = tid & 1;
            unsigned u = (isZ ? 3u : 1u) << (2*i);
            cvec[2*TQ[i] + isZ] = tile[swz(u)];
        }
    } else if (tid == 0){
        const int BQ[4] = {4,3,2,1};
#pragma unroll
        for (int j=0; j<4; j++){
            if (blk == (1u<<(2*j))) cvec[2*BQ[j]]   = tile[0];
            if (blk == (3u<<(2*j))) cvec[2*BQ[j]+1] = tile[0];
        }
    }
}

// ================= head: logits + sigmoid =================
__global__ void __launch_bounds__(256)
logits_kernel(const float* __restrict__ x, const float* __restrict__ bvec,
              const float* __restrict__ cvec, const float* __restrict__ w,
              float* __restrict__ out)
{
    __shared__ float xs[1024];
    __shared__ float cX[10], cZ[10];
    __shared__ float red[4];
    int b = blockIdx.x, tid = threadIdx.x;
    if (tid < 10){
        cX[tid] = w[2*tid] * cvec[2*tid];
        cZ[tid] = 0.96f * w[2*tid+1] * cvec[2*tid+1];   // readout bitflip folded: Z *= 1-2*0.02
    }
    {
        float4 xv = reinterpret_cast<const float4*>(x + (size_t)b*1024)[tid];
        float4 bv = reinterpret_cast<const float4*>(bvec)[tid];
        xs[tid*4+0] = xv.x + bv.x;
        xs[tid*4+1] = xv.y + bv.y;
        xs[tid*4+2] = xv.z + bv.z;
        xs[tid*4+3] = xv.w + bv.w;
    }
    __syncthreads();
    float acc = 0.f;
#pragma unroll
    for (int r=0; r<4; r++){
        int m = tid + r*256;
        float xm = xs[m];
        float sd = 0.f;
#pragma unroll
        for (int qq=0; qq<10; qq++){
            float cz = cZ[qq];
            sd += (m & (1<<(9-qq))) ? -cz : cz;
            acc += cX[qq] * xm * xs[m ^ (1<<(9-qq))];
        }
        acc += sd * xm * xm;
    }
    for (int o=32; o>0; o>>=1) acc += __shfl_down(acc, o);
    if ((tid & 63) == 0) red[tid>>6] = acc;
    __syncthreads();
    if (tid == 0){
        float l = red[0]+red[1]+red[2]+red[3];
        out[b] = 1.f / (1.f + expf(-l));
    }
}

// ================= launch =================
extern "C" void kernel_launch(void* const* d_in, const int* in_sizes, int n_in,
                              void* d_out, int out_size, void* d_ws, size_t ws_size,
                              hipStream_t stream) {
    const float* x    = (const float*)d_in[0];   // [2048,1024]
    const float* bvec = (const float*)d_in[1];   // [1024]
    const float* w    = (const float*)d_in[2];   // [20]
    const float* cw   = (const float*)d_in[3];   // [3,10,3]
    float* out = (float*)d_out;

    char* ws = (char*)d_ws;
    float* rho  = (float*)ws;                                    // 2^20 floats = 4 MB
    float* cvec = (float*)(ws + (size_t)(1u<<20)*sizeof(float));
    (void)ws_size; (void)in_sizes; (void)n_in; (void)out_size;

    fused6<0,0,1,0><<<256, 256, 0, stream>>>(rho, cw, cvec);
    fused6<0,1,0,0><<<256, 256, 0, stream>>>(rho, cw, cvec);
    fused6<1,0,0,0><<<256, 256, 0, stream>>>(rho, cw, cvec);
    fused6<1,1,0,0><<<256, 256, 0, stream>>>(rho, cw, cvec);
    fused6<2,0,0,0><<<256, 256, 0, stream>>>(rho, cw, cvec);
    fused6<2,1,0,2><<<9,   256, 0, stream>>>(rho, cw, cvec);
    logits_kernel<<<2048, 256, 0, stream>>>(x, bvec, cvec, w, out);
}